// Round 1
// 517.302 us; speedup vs baseline: 1.0336x; 1.0336x over previous
//
#include <hip/hip_runtime.h>
#include <cstdint>
#include <cstddef>

#define TSEQ 2048
#define DDIM 1024

typedef _Float16 f16;
typedef _Float16 f16x2 __attribute__((ext_vector_type(2)));
typedef _Float16 f16x4 __attribute__((ext_vector_type(4)));
typedef _Float16 f16x8 __attribute__((ext_vector_type(8)));
typedef float f32x4 __attribute__((ext_vector_type(4)));

// q,k,v live in (b,h,t,d) layout: ((b*16+h)*2048 + t)*64 + d.
// Conv weights: wh[o][w*1024 + i] (K-contiguous for the GEMM B side).

__device__ __align__(16) static const unsigned char g_zero16[16] = {};

__device__ __forceinline__ void gload_lds16(const void* g, void* l) {
  __builtin_amdgcn_global_load_lds(
      (const __attribute__((address_space(1))) void*)g,
      (__attribute__((address_space(3))) void*)l, 16, 0, 0);
}

// ------------- fused fp32->fp16 converts (x, v_w, p_w) -------------
__global__ void cvt_all(const float* __restrict__ x, const float* __restrict__ vw,
                        const float* __restrict__ pw,
                        f16* __restrict__ xh, f16* __restrict__ vwh, f16* __restrict__ pwh) {
  int b = blockIdx.x;
  const float* src; f16* dst; int i;
  if (b < 4096)      { src = x;  dst = xh;  i = b * 256 + threadIdx.x; }
  else if (b < 5120) { src = vw; dst = vwh; i = (b - 4096) * 256 + threadIdx.x; }
  else               { src = pw; dst = pwh; i = (b - 5120) * 256 + threadIdx.x; }
  float4 v = ((const float4*)src)[i];
  f16x4 h = { (f16)v.x, (f16)v.y, (f16)v.z, (f16)v.w };
  ((f16x4*)dst)[i] = h;
}

// ------- conv weights w[o][i][W] -> wh[o][w*1024+i], vectorized both sides -------
__global__ __launch_bounds__(256) void cvt_w_tr(const float* __restrict__ qw,
                                                const float* __restrict__ kw,
                                                f16* __restrict__ qd, f16* __restrict__ kd) {
  __shared__ f16 tile[16][1032];   // [w][i], +16B pad per row
  const int o = blockIdx.x;
  const float* src; f16* dst;
  if (o < 1024) { src = qw + (size_t)o * 16384; dst = qd + (size_t)o * 16384; }
  else          { src = kw + (size_t)(o - 1024) * 16384; dst = kd + (size_t)(o - 1024) * 16384; }
  const int tid = threadIdx.x;
  #pragma unroll
  for (int p = 0; p < 16; p++) {
    const int idx = p * 256 + tid;          // 0..4095
    const int i = idx >> 2, wq = idx & 3;   // i-channel 0..1023, w-quad 0..3
    float4 v = *(const float4*)(src + (size_t)i * 16 + wq * 4);
    tile[wq * 4 + 0][i] = (f16)v.x;
    tile[wq * 4 + 1][i] = (f16)v.y;
    tile[wq * 4 + 2][i] = (f16)v.z;
    tile[wq * 4 + 3][i] = (f16)v.w;
  }
  __syncthreads();
  #pragma unroll
  for (int p = 0; p < 8; p++) {
    const int c = p * 256 + tid;            // 0..2047
    const int w = c >> 7, i8 = (c & 127) * 8;
    *(f16x8*)(dst + (size_t)w * 1024 + i8) = *(const f16x8*)&tile[w][i8];
  }
}

// ------------- fused q+k conv-GEMM, 8-wave 256x(64|64), counted-vmcnt pipeline -------------
// BM=256, BK=64, 3-deep LDS pipeline (3 x 48KB), 2 phases/K-tile (16 MFMA each),
// raw s_barrier + s_waitcnt vmcnt(6) (never 0 in steady state), setprio around MFMA.
// Per-buffer LDS layout (f16 units): As[256*64] @0, Bqs[64*64] @16384, Bks[64*64] @20480.
__global__ __launch_bounds__(512, 1) void gemm_qk8(
    const f16* __restrict__ xh,
    const f16* __restrict__ Bq, const f16* __restrict__ Bk,
    const float* __restrict__ bq, const float* __restrict__ bk,
    f16* __restrict__ oq, f16* __restrict__ ok)
{
  extern __shared__ __align__(16) f16 smem[];   // 3 * 24576 f16 = 144 KB
  const int tid = threadIdx.x;
  const int lane = tid & 63;
  const int wid = tid >> 6;          // 0..7
  const int wq = wid >> 1;           // M-quarter 0..3 (64 rows each)
  const int wp = wid & 1;            // 0 = q projection, 1 = k projection

  const int m0 = blockIdx.x * 256;
  const int n0 = blockIdx.y * 64;
  const int bT = m0 & ~(TSEQ - 1);
  const int t0 = m0 & (TSEQ - 1);

  // staging swizzle: lane l -> row-in-group l>>3, LDS slot l&7, global chunk (l&7)^(srow&7)
  const int srow = lane >> 3;
  const int chunk8 = (((lane & 7) ^ (srow & 7)) << 3);

  f32x4 acc[4][4] = {};

  auto stageA = [&](int kt, int buf) {     // 4 gload_lds per wave: A rows wid*32..+31
    const int kk = kt << 6;
    const int w = kk >> 10;
    const int i0 = kk & (DDIM - 1);
    f16* sb = smem + buf * 24576;
    #pragma unroll
    for (int c = 0; c < 4; c++) {
      const int rr = wid * 32 + c * 8;
      const int srcT = t0 + rr + srow + w - 15;
      const void* g = (srcT >= 0)
          ? (const void*)(xh + (((size_t)(bT + srcT)) << 10) + i0 + chunk8)
          : (const void*)g_zero16;
      gload_lds16(g, (void*)&sb[rr * 64]);
    }
  };
  auto stageB = [&](int kt, int buf) {     // 2 gload_lds per wave: waves 0-3 Bq, 4-7 Bk
    const int kk = kt << 6;
    f16* sb = smem + buf * 24576 + (wid < 4 ? 16384 : 20480);
    const f16* Bsrc = (wid < 4) ? Bq : Bk;
    const int wb = wid & 3;
    #pragma unroll
    for (int c = 0; c < 2; c++) {
      const int rr = wb * 16 + c * 8;
      const void* g = (const void*)(Bsrc + (((size_t)(n0 + rr + srow)) << 14) + kk + chunk8);
      gload_lds16(g, (void*)&sb[rr * 64]);
    }
  };

  // prologue: 2 tiles in flight (12 outstanding loads per wave)
  stageA(0, 0); stageB(0, 0);
  stageA(1, 1); stageB(1, 1);

  const int NT = 16384 / 64;   // 256 K-tiles
  int buf = 0;
  for (int kt = 0; kt < NT; kt++) {
    // tile-boundary wait: oldest 6 (tile kt) landed; tile kt+1 stays in flight
    if (kt < NT - 1) {
      asm volatile("s_waitcnt vmcnt(6)" ::: "memory");
    } else {
      asm volatile("s_waitcnt vmcnt(0)" ::: "memory");
    }
    __builtin_amdgcn_s_barrier();
    __builtin_amdgcn_sched_barrier(0);

    const f16* sb = smem + buf * 24576;
    const f16* bsb = sb + (wp ? 20480 : 16384);
    const int stq = kt + 2;
    const int sbuf = (buf >= 1) ? buf - 1 : 2;   // (kt+2) % 3

    // ---- phase 0: K-slice 0 (chunks 0..3) ----
    {
      const int slot = (((lane >> 4)) ^ (lane & 7)) << 3;
      f16x8 af[4], bf[4];
      #pragma unroll
      for (int i = 0; i < 4; i++)
        af[i] = *(const f16x8*)&sb[(wq * 64 + i * 16 + (lane & 15)) * 64 + slot];
      #pragma unroll
      for (int j = 0; j < 4; j++)
        bf[j] = *(const f16x8*)&bsb[(j * 16 + (lane & 15)) * 64 + slot];
      if (stq < NT) stageA(stq, sbuf);
      __builtin_amdgcn_s_barrier();
      asm volatile("s_waitcnt lgkmcnt(0)" ::: "memory");
      __builtin_amdgcn_sched_barrier(0);
      __builtin_amdgcn_s_setprio(1);
      #pragma unroll
      for (int i = 0; i < 4; i++)
        #pragma unroll
        for (int j = 0; j < 4; j++)
          acc[i][j] = __builtin_amdgcn_mfma_f32_16x16x32_f16(af[i], bf[j], acc[i][j], 0, 0, 0);
      __builtin_amdgcn_s_setprio(0);
    }

    // ---- phase 1: K-slice 1 (chunks 4..7) ----
    {
      const int slot = ((4 + (lane >> 4)) ^ (lane & 7)) << 3;
      f16x8 af[4], bf[4];
      #pragma unroll
      for (int i = 0; i < 4; i++)
        af[i] = *(const f16x8*)&sb[(wq * 64 + i * 16 + (lane & 15)) * 64 + slot];
      #pragma unroll
      for (int j = 0; j < 4; j++)
        bf[j] = *(const f16x8*)&bsb[(j * 16 + (lane & 15)) * 64 + slot];
      if (stq < NT) stageB(stq, sbuf);
      __builtin_amdgcn_s_barrier();
      asm volatile("s_waitcnt lgkmcnt(0)" ::: "memory");
      __builtin_amdgcn_sched_barrier(0);
      __builtin_amdgcn_s_setprio(1);
      #pragma unroll
      for (int i = 0; i < 4; i++)
        #pragma unroll
        for (int j = 0; j < 4; j++)
          acc[i][j] = __builtin_amdgcn_mfma_f32_16x16x32_f16(af[i], bf[j], acc[i][j], 0, 0, 0);
      __builtin_amdgcn_s_setprio(0);
    }

    buf = (buf == 2) ? 0 : buf + 1;
  }

  // ---- epilogue: bias add + direct (b,h,t,d) write. C/D: col=lane&15, row=(lane>>4)*4+reg ----
  const int crow = (lane >> 4) << 2;
  const int ccol = lane & 15;
  const int hh = n0 >> 6;
  const float* bias = wp ? bk : bq;
  f16* outp = wp ? ok : oq;
  #pragma unroll
  for (int j = 0; j < 4; j++) {
    const int col = n0 + j * 16 + ccol;
    const float bvl = bias[col];
    const int d = (j << 4) + ccol;
    #pragma unroll
    for (int i = 0; i < 4; i++) {
      #pragma unroll
      for (int r = 0; r < 4; r++) {
        const int row = m0 + wq * 64 + i * 16 + crow + r;
        const int b = row >> 11, t = row & (TSEQ - 1);
        outp[((size_t)(b * 16 + hh) * TSEQ + t) * 64 + d] = (f16)(acc[i][j][r] + bvl);
      }
    }
  }
}

// ---------------- small GEMM (K=1024): v-proj / p-proj ----------------
// MODE 0: fp16 out to (b,h,t,d) layout (v). MODE 1: fp32 out to (b,t,d) d_out (p).
template<int MODE>
__global__ __launch_bounds__(256, 2) void gemm_small(
    const f16* __restrict__ A, const f16* __restrict__ Bw,
    const float* __restrict__ bias, f16* __restrict__ oh, float* __restrict__ ofp)
{
  __shared__ f16 As[128 * 32];
  __shared__ f16 Bs[128 * 32];
  const int tid = threadIdx.x;
  const int lane = tid & 63;
  const int wid = tid >> 6;
  const int m0 = blockIdx.x * 128;
  const int n0 = blockIdx.y * 128;

  const int srow = lane >> 2;
  const int scg = ((lane & 3) ^ ((lane >> 3) & 3)) * 8;
  const int wm = wid & 1;
  const int wn = wid >> 1;

  f32x4 acc[4][4] = {};

  for (int kk = 0; kk < 1024; kk += 32) {
    __syncthreads();
    if (wid < 2) {
      #pragma unroll
      for (int c = 0; c < 4; c++) {
        const int r = wid * 64 + c * 16 + srow;
        const void* g = (const void*)(A + (((size_t)(m0 + r)) << 10) + kk + scg);
        gload_lds16(g, (void*)&As[(wid * 64 + c * 16) * 32]);
      }
    } else {
      #pragma unroll
      for (int c = 0; c < 4; c++) {
        const int r = (wid - 2) * 64 + c * 16 + srow;
        const void* g = (const void*)(Bw + (((size_t)(n0 + r)) << 10) + kk + scg);
        gload_lds16(g, (void*)&Bs[((wid - 2) * 64 + c * 16) * 32]);
      }
    }
    __syncthreads();
    const int koff = ((lane >> 4) ^ ((lane >> 1) & 3)) * 8;
    f16x8 af[4], bf[4];
    #pragma unroll
    for (int i = 0; i < 4; i++) {
      af[i] = *(const f16x8*)&As[(wm * 64 + i * 16 + (lane & 15)) * 32 + koff];
      bf[i] = *(const f16x8*)&Bs[(wn * 64 + i * 16 + (lane & 15)) * 32 + koff];
    }
    #pragma unroll
    for (int i = 0; i < 4; i++)
      #pragma unroll
      for (int j = 0; j < 4; j++)
        acc[i][j] = __builtin_amdgcn_mfma_f32_16x16x32_f16(af[i], bf[j], acc[i][j], 0, 0, 0);
  }

  const int crow = (lane >> 4) * 4;
  const int ccol = lane & 15;
  #pragma unroll
  for (int j = 0; j < 4; j++) {
    const int col = n0 + wn * 64 + j * 16 + ccol;
    const float bvl = bias[col];
    #pragma unroll
    for (int i = 0; i < 4; i++) {
      #pragma unroll
      for (int r = 0; r < 4; r++) {
        const int row = m0 + wm * 64 + i * 16 + crow + r;
        const float val = acc[i][j][r] + bvl;
        if (MODE == 1) {
          ofp[(size_t)row * DDIM + col] = val;
        } else {
          const int b = row >> 11, t = row & (TSEQ - 1);
          const int h = col >> 6, d = col & 63;
          oh[((size_t)(b * 16 + h) * TSEQ + t) * 64 + d] = (f16)val;
        }
      }
    }
  }
}

// ------- log-sparse scores, (b,h,t,d) layout, coalesced + fdot2 -------
__global__ __launch_bounds__(256) void score_k(const f16* __restrict__ qh,
                                               const f16* __restrict__ kh,
                                               float* __restrict__ scores) {
  const int bid = blockIdx.x;
  const int bh = bid >> 5, tc = bid & 31;
  const int tid = threadIdx.x;
  const int wave = tid >> 6, lane = tid & 63;
  const int tr = lane >> 3, dc = lane & 7;
  const size_t base = ((size_t)bh) << 17;
  const f16* qb = qh + base;
  const f16* kb = kh + base;

  #pragma unroll
  for (int p = 0; p < 2; p++) {
    const int t = tc * 64 + p * 32 + wave * 8 + tr;
    f16x8 qv = *(const f16x8*)(qb + (size_t)t * 64 + dc * 8);
    const f16x2* qp = (const f16x2*)&qv;
    #pragma unroll
    for (int e = 0; e < 8; e++) {
      const int ts = (t + (1 << e)) & (TSEQ - 1);
      f16x8 kv = *(const f16x8*)(kb + (size_t)ts * 64 + dc * 8);
      const f16x2* kp = (const f16x2*)&kv;
      float s = 0.f;
      #pragma unroll
      for (int j = 0; j < 4; j++) s = __builtin_amdgcn_fdot2(qp[j], kp[j], s, false);
      s += __shfl_xor(s, 1, 64);
      s += __shfl_xor(s, 2, 64);
      s += __shfl_xor(s, 4, 64);
      if (dc == 0) scores[((size_t)(bh * 8 + e) << 11) + t] = s * 0.125f;
    }
  }
}

// ---- in-place softmax over T per (b,h,e) row: 256 rows of 2048 ----
__global__ void softmax_k(float* __restrict__ scores) {
  __shared__ float red[4];
  int row = blockIdx.x;
  float* p = scores + ((size_t)row << 11);
  int tid = threadIdx.x;
  float v[8];
  float4 a = ((const float4*)p)[tid * 2];
  float4 b = ((const float4*)p)[tid * 2 + 1];
  v[0] = a.x; v[1] = a.y; v[2] = a.z; v[3] = a.w;
  v[4] = b.x; v[5] = b.y; v[6] = b.z; v[7] = b.w;
  float m = v[0];
  #pragma unroll
  for (int j = 1; j < 8; j++) m = fmaxf(m, v[j]);
  for (int o = 32; o > 0; o >>= 1) m = fmaxf(m, __shfl_xor(m, o, 64));
  if ((tid & 63) == 0) red[tid >> 6] = m;
  __syncthreads();
  m = fmaxf(fmaxf(red[0], red[1]), fmaxf(red[2], red[3]));
  __syncthreads();
  float s = 0.f;
  #pragma unroll
  for (int j = 0; j < 8; j++) { v[j] = __expf(v[j] - m); s += v[j]; }
  for (int o = 32; o > 0; o >>= 1) s += __shfl_xor(s, o, 64);
  if ((tid & 63) == 0) red[tid >> 6] = s;
  __syncthreads();
  s = (red[0] + red[1]) + (red[2] + red[3]);
  float inv = 1.0f / s;
  float4 o1 = make_float4(v[0] * inv, v[1] * inv, v[2] * inv, v[3] * inv);
  float4 o2 = make_float4(v[4] * inv, v[5] * inv, v[6] * inv, v[7] * inv);
  ((float4*)p)[tid * 2] = o1;
  ((float4*)p)[tid * 2 + 1] = o2;
}

// ------- local windowed attention + log-sparse combine -> outh (b,t,d) -------
__global__ __launch_bounds__(256) void attn_out_k(
    const f16* __restrict__ qh, const f16* __restrict__ kh, const f16* __restrict__ vh,
    const float* __restrict__ alpha, f16* __restrict__ outh)
{
  __shared__ f16 qL[64 * 64];
  __shared__ f16 kL[80 * 64];
  __shared__ f16 vL[208 * 64];
  __shared__ float scL[64 * 16];
  __shared__ float aL[8 * 64];
  const int bh = blockIdx.x, tc = blockIdx.y;
  const int t0 = tc * 64;
  const int tid = threadIdx.x;
  const size_t base = ((size_t)bh) << 17;

  for (int idx = tid; idx < 64 * 8; idx += 256) {
    int r = idx >> 3, c = idx & 7, sl = c ^ (r & 7);
    *(uint4*)&qL[r * 64 + sl * 8] = *(const uint4*)(qh + base + (size_t)(t0 + r) * 64 + c * 8);
  }
  for (int idx = tid; idx < 79 * 8; idx += 256) {
    int r = idx >> 3, c = idx & 7, sl = c ^ (r & 7);
    int g = t0 - 15 + r;
    uint4 val = (g < 0) ? make_uint4(0, 0, 0, 0)
                        : *(const uint4*)(kh + base + (size_t)g * 64 + c * 8);
    *(uint4*)&kL[r * 64 + sl * 8] = val;
  }
  for (int idx = tid; idx < 207 * 8; idx += 256) {
    int r = idx >> 3, c = idx & 7, sl = c ^ (r & 7);
    int g = t0 - 15 + r;
    uint4 val;
    if (g < 0) val = make_uint4(0, 0, 0, 0);
    else {
      if (g >= TSEQ) g -= TSEQ;
      val = *(const uint4*)(vh + base + (size_t)g * 64 + c * 8);
    }
    *(uint4*)&vL[r * 64 + sl * 8] = val;
  }
  for (int idx = tid; idx < 512; idx += 256) {
    int e = idx >> 6, i = idx & 63;
    aL[e * 64 + i] = alpha[((size_t)(bh * 8 + e) << 11) + t0 + i];
  }
  __syncthreads();

  {
    const int tl = tid & 63;
    const int wg = tid >> 6;
    f16x8 qv[8];
    #pragma unroll
    for (int c = 0; c < 8; c++) qv[c] = *(const f16x8*)&qL[tl * 64 + ((c ^ (tl & 7)) * 8)];
    const f16x2* qp = (const f16x2*)&qv[0];
    #pragma unroll
    for (int wi = 0; wi < 4; wi++) {
      const int w = wg * 4 + wi;
      const int r = tl + w;
      float s = 0.f;
      #pragma unroll
      for (int c = 0; c < 8; c++) {
        f16x8 kv = *(const f16x8*)&kL[r * 64 + ((c ^ (r & 7)) * 8)];
        const f16x2* kp = (const f16x2*)&kv;
        #pragma unroll
        for (int j = 0; j < 4; j++) s = __builtin_amdgcn_fdot2(qp[c * 4 + j], kp[j], s, false);
      }
      scL[tl * 16 + w] = s * 0.125f;
    }
  }
  __syncthreads();

  if (tid < 64) {
    float sc[16];
    float m = -1e30f;
    #pragma unroll
    for (int w = 0; w < 16; w++) { sc[w] = scL[tid * 16 + w]; m = fmaxf(m, sc[w]); }
    float sum = 0.f;
    #pragma unroll
    for (int w = 0; w < 16; w++) { sc[w] = __expf(sc[w] - m); sum += sc[w]; }
    float inv = 1.0f / sum;
    #pragma unroll
    for (int w = 0; w < 16; w++) scL[tid * 16 + w] = sc[w] * inv;
  }
  __syncthreads();

  {
    const int tl = tid >> 2;
    const int qd = tid & 3;
    float accv[16] = {};
    #pragma unroll
    for (int w = 0; w < 16; w++) {
      const float pw_ = scL[tl * 16 + w];
      const int r = tl + w;
      #pragma unroll
      for (int c2 = 0; c2 < 2; c2++) {
        const int c = qd * 2 + c2;
        f16x8 v = *(const f16x8*)&vL[r * 64 + ((c ^ (r & 7)) * 8)];
        #pragma unroll
        for (int j = 0; j < 8; j++) accv[c2 * 8 + j] += pw_ * (float)v[j];
      }
    }
    #pragma unroll
    for (int e = 0; e < 8; e++) {
      const float a = aL[e * 64 + tl];
      const int r = tl + 15 + (1 << e);
      #pragma unroll
      for (int c2 = 0; c2 < 2; c2++) {
        const int c = qd * 2 + c2;
        f16x8 v = *(const f16x8*)&vL[r * 64 + ((c ^ (r & 7)) * 8)];
        #pragma unroll
        for (int j = 0; j < 8; j++) accv[c2 * 8 + j] += a * (float)v[j];
      }
    }
    const int b = bh >> 4, h = bh & 15;
    f16* orow = outh + ((size_t)(b * TSEQ + t0 + tl)) * DDIM + h * 64 + qd * 16;
    #pragma unroll
    for (int c2 = 0; c2 < 2; c2++) {
      f16x8 v;
      #pragma unroll
      for (int j = 0; j < 8; j++) v[j] = (f16)accv[c2 * 8 + j];
      *(f16x8*)(orow + c2 * 8) = v;
    }
  }
}

extern "C" void kernel_launch(void* const* d_in, const int* in_sizes, int n_in,
                              void* d_out, int out_size, void* d_ws, size_t ws_size,
                              hipStream_t stream) {
  (void)in_sizes; (void)n_in; (void)out_size; (void)ws_size;
  const float* x   = (const float*)d_in[0];
  const float* q_w = (const float*)d_in[1];
  const float* q_b = (const float*)d_in[2];
  const float* k_w = (const float*)d_in[3];
  const float* k_b = (const float*)d_in[4];
  const float* v_w = (const float*)d_in[5];
  const float* v_b = (const float*)d_in[6];
  const float* p_w = (const float*)d_in[7];
  const float* p_b = (const float*)d_in[8];
  float* out = (float*)d_out;

  char* ws = (char*)d_ws;
  f16* xh      = (f16*)(ws);                 //  8.4 MB (b,t,d)
  f16* qwh     = (f16*)(ws + 8388608);       // 33.6 MB [o][w*1024+i]
  f16* kwh     = (f16*)(ws + 41943040);      // 33.6 MB [o][w*1024+i]
  f16* vwh     = (f16*)(ws + 75497472);      //  2.1 MB flat [o][k]
  f16* pwh     = (f16*)(ws + 77594624);      //  2.1 MB flat [o][k]
  f16* qh      = (f16*)(ws + 79691776);      //  8.4 MB (b,h,t,d)
  f16* kh      = (f16*)(ws + 88080384);      //  8.4 MB (b,h,t,d)
  f16* vh      = (f16*)(ws + 96468992);      //  8.4 MB (b,h,t,d)
  f16* outh    = (f16*)(ws + 104857600);     //  8.4 MB (b,t,d)
  float* alpha = (float*)(ws + 113246208);   //  2.1 MB (B*H*E, T)
  // total 115.4 MB

  static int s_attr_done = 0;
  if (!s_attr_done) {
    hipFuncSetAttribute((const void*)gemm_qk8,
                        hipFuncAttributeMaxDynamicSharedMemorySize, 147456);
    s_attr_done = 1;
  }

  cvt_all<<<6144, 256, 0, stream>>>(x, v_w, p_w, xh, vwh, pwh);
  cvt_w_tr<<<2048, 256, 0, stream>>>(q_w, k_w, qwh, kwh);

  // fused q+k conv-GEMM, 256 blocks = 1/CU, 144KB dynamic LDS, counted-vmcnt pipeline
  gemm_qk8<<<dim3(16, 16), 512, 147456, stream>>>(xh, qwh, kwh, q_b, k_b, qh, kh);
  // v projection
  gemm_small<0><<<dim3(32, 8), 256, 0, stream>>>(xh, vwh, v_b, vh, nullptr);

  score_k<<<1024, 256, 0, stream>>>(qh, kh, alpha);
  softmax_k<<<256, 256, 0, stream>>>(alpha);
  attn_out_k<<<dim3(32, 32), 256, 0, stream>>>(qh, kh, vh, alpha, outh);

  // final projection -> fp32 d_out
  gemm_small<1><<<dim3(32, 8), 256, 0, stream>>>(outh, pwh, p_b, nullptr, out);
}

// Round 2
// 513.981 us; speedup vs baseline: 1.0403x; 1.0065x over previous
//
#include <hip/hip_runtime.h>
#include <cstdint>
#include <cstddef>

#define TSEQ 2048
#define DDIM 1024

typedef _Float16 f16;
typedef _Float16 f16x2 __attribute__((ext_vector_type(2)));
typedef _Float16 f16x4 __attribute__((ext_vector_type(4)));
typedef _Float16 f16x8 __attribute__((ext_vector_type(8)));
typedef float f32x4 __attribute__((ext_vector_type(4)));

// q,k,v live in (b,h,t,d) layout: ((b*16+h)*2048 + t)*64 + d.
// Conv weights: wh[o][w*1024 + i] (K-contiguous for the GEMM B side).

__device__ __align__(16) static const unsigned char g_zero16[16] = {};

__device__ __forceinline__ void gload_lds16(const void* g, void* l) {
  __builtin_amdgcn_global_load_lds(
      (const __attribute__((address_space(1))) void*)g,
      (__attribute__((address_space(3))) void*)l, 16, 0, 0);
}

// ------------- fused fp32->fp16 converts (x, v_w, p_w) -------------
__global__ void cvt_all(const float* __restrict__ x, const float* __restrict__ vw,
                        const float* __restrict__ pw,
                        f16* __restrict__ xh, f16* __restrict__ vwh, f16* __restrict__ pwh) {
  int b = blockIdx.x;
  const float* src; f16* dst; int i;
  if (b < 4096)      { src = x;  dst = xh;  i = b * 256 + threadIdx.x; }
  else if (b < 5120) { src = vw; dst = vwh; i = (b - 4096) * 256 + threadIdx.x; }
  else               { src = pw; dst = pwh; i = (b - 5120) * 256 + threadIdx.x; }
  float4 v = ((const float4*)src)[i];
  f16x4 h = { (f16)v.x, (f16)v.y, (f16)v.z, (f16)v.w };
  ((f16x4*)dst)[i] = h;
}

// ------- conv weights w[o][i][W] -> wh[o][w*1024+i], vectorized both sides -------
__global__ __launch_bounds__(256) void cvt_w_tr(const float* __restrict__ qw,
                                                const float* __restrict__ kw,
                                                f16* __restrict__ qd, f16* __restrict__ kd) {
  __shared__ f16 tile[16][1032];   // [w][i], +16B pad per row
  const int o = blockIdx.x;
  const float* src; f16* dst;
  if (o < 1024) { src = qw + (size_t)o * 16384; dst = qd + (size_t)o * 16384; }
  else          { src = kw + (size_t)(o - 1024) * 16384; dst = kd + (size_t)(o - 1024) * 16384; }
  const int tid = threadIdx.x;
  #pragma unroll
  for (int p = 0; p < 16; p++) {
    const int idx = p * 256 + tid;          // 0..4095
    const int i = idx >> 2, wq = idx & 3;   // i-channel 0..1023, w-quad 0..3
    float4 v = *(const float4*)(src + (size_t)i * 16 + wq * 4);
    tile[wq * 4 + 0][i] = (f16)v.x;
    tile[wq * 4 + 1][i] = (f16)v.y;
    tile[wq * 4 + 2][i] = (f16)v.z;
    tile[wq * 4 + 3][i] = (f16)v.w;
  }
  __syncthreads();
  #pragma unroll
  for (int p = 0; p < 8; p++) {
    const int c = p * 256 + tid;            // 0..2047
    const int w = c >> 7, i8 = (c & 127) * 8;
    *(f16x8*)(dst + (size_t)w * 1024 + i8) = *(const f16x8*)&tile[w][i8];
  }
}

// ------------- fused q+k conv-GEMM, 8-wave 256x(64|64), 1-barrier/K-tile -------------
// BM=256, BK=64, 3-deep LDS pipeline (3 x 48KB). ONE s_barrier per K-tile:
//   RAW (stage->read) covered by vmcnt(6)+barrier at tile top;
//   WAR (read->restage) covered by lgkmcnt(0) folded into the same top wait.
// Both phases' fragments loaded up-front (compiler emits lgkmcnt(8) before MFMA0);
// stage-issues interleaved between the two MFMA clusters; setprio around MFMA.
// Per-buffer LDS layout (f16 units): As[256*64] @0, Bqs[64*64] @16384, Bks[64*64] @20480.
__global__ __launch_bounds__(512, 1) void gemm_qk8(
    const f16* __restrict__ xh,
    const f16* __restrict__ Bq, const f16* __restrict__ Bk,
    const float* __restrict__ bq, const float* __restrict__ bk,
    f16* __restrict__ oq, f16* __restrict__ ok)
{
  extern __shared__ __align__(16) f16 smem[];   // 3 * 24576 f16 = 144 KB
  const int tid = threadIdx.x;
  const int lane = tid & 63;
  const int wid = tid >> 6;          // 0..7
  const int wq = wid >> 1;           // M-quarter 0..3 (64 rows each)
  const int wp = wid & 1;            // 0 = q projection, 1 = k projection

  const int m0 = blockIdx.x * 256;
  const int n0 = blockIdx.y * 64;
  const int bT = m0 & ~(TSEQ - 1);
  const int t0 = m0 & (TSEQ - 1);

  // staging swizzle: lane l -> row-in-group l>>3, LDS slot l&7, global chunk (l&7)^(srow&7)
  const int srow = lane >> 3;
  const int chunk8 = (((lane & 7) ^ (srow & 7)) << 3);

  f32x4 acc[4][4] = {};

  auto stageA = [&](int kt, int buf) {     // 4 gload_lds per wave: A rows wid*32..+31
    const int kk = kt << 6;
    const int w = kk >> 10;
    const int i0 = kk & (DDIM - 1);
    f16* sb = smem + buf * 24576;
    #pragma unroll
    for (int c = 0; c < 4; c++) {
      const int rr = wid * 32 + c * 8;
      const int srcT = t0 + rr + srow + w - 15;
      const void* g = (srcT >= 0)
          ? (const void*)(xh + (((size_t)(bT + srcT)) << 10) + i0 + chunk8)
          : (const void*)g_zero16;
      gload_lds16(g, (void*)&sb[rr * 64]);
    }
  };
  auto stageB = [&](int kt, int buf) {     // 2 gload_lds per wave: waves 0-3 Bq, 4-7 Bk
    const int kk = kt << 6;
    f16* sb = smem + buf * 24576 + (wid < 4 ? 16384 : 20480);
    const f16* Bsrc = (wid < 4) ? Bq : Bk;
    const int wb = wid & 3;
    #pragma unroll
    for (int c = 0; c < 2; c++) {
      const int rr = wb * 16 + c * 8;
      const void* g = (const void*)(Bsrc + (((size_t)(n0 + rr + srow)) << 14) + kk + chunk8);
      gload_lds16(g, (void*)&sb[rr * 64]);
    }
  };

  // prologue: 2 tiles in flight (12 outstanding loads per wave)
  stageA(0, 0); stageB(0, 0);
  stageA(1, 1); stageB(1, 1);

  const int NT = 16384 / 64;   // 256 K-tiles
  int buf = 0;
  for (int kt = 0; kt < NT; kt++) {
    // Tile-boundary wait. vmcnt: oldest 6 (tile kt's stages, CU-wide after barrier)
    // landed; tile kt+1's 6 stay in flight. lgkmcnt(0): this wave's ds_reads of the
    // buffer about to be re-staged are complete (WAR fence, since MFMAs may sink).
    if (kt < NT - 1) {
      asm volatile("s_waitcnt vmcnt(6) lgkmcnt(0)" ::: "memory");
    } else {
      asm volatile("s_waitcnt vmcnt(0) lgkmcnt(0)" ::: "memory");
    }
    __builtin_amdgcn_s_barrier();
    __builtin_amdgcn_sched_barrier(0);

    const f16* sb = smem + buf * 24576;
    const f16* bsb = sb + (wp ? 20480 : 16384);
    const int stq = kt + 2;
    const int sbuf = (buf >= 1) ? buf - 1 : 2;   // (kt+2) % 3

    // read-side swizzle slots for the two K-slices of this tile
    const int slot0 = (((lane >> 4)) ^ (lane & 7)) << 3;
    const int slot1 = ((4 + (lane >> 4)) ^ (lane & 7)) << 3;

    f16x8 af0[4], bf0[4], af1[4], bf1[4];
    #pragma unroll
    for (int i = 0; i < 4; i++)
      af0[i] = *(const f16x8*)&sb[(wq * 64 + i * 16 + (lane & 15)) * 64 + slot0];
    #pragma unroll
    for (int j = 0; j < 4; j++)
      bf0[j] = *(const f16x8*)&bsb[(j * 16 + (lane & 15)) * 64 + slot0];
    #pragma unroll
    for (int i = 0; i < 4; i++)
      af1[i] = *(const f16x8*)&sb[(wq * 64 + i * 16 + (lane & 15)) * 64 + slot1];
    #pragma unroll
    for (int j = 0; j < 4; j++)
      bf1[j] = *(const f16x8*)&bsb[(j * 16 + (lane & 15)) * 64 + slot1];

    if (stq < NT) stageA(stq, sbuf);

    __builtin_amdgcn_s_setprio(1);
    #pragma unroll
    for (int i = 0; i < 4; i++)
      #pragma unroll
      for (int j = 0; j < 4; j++)
        acc[i][j] = __builtin_amdgcn_mfma_f32_16x16x32_f16(af0[i], bf0[j], acc[i][j], 0, 0, 0);
    __builtin_amdgcn_s_setprio(0);

    if (stq < NT) stageB(stq, sbuf);

    __builtin_amdgcn_s_setprio(1);
    #pragma unroll
    for (int i = 0; i < 4; i++)
      #pragma unroll
      for (int j = 0; j < 4; j++)
        acc[i][j] = __builtin_amdgcn_mfma_f32_16x16x32_f16(af1[i], bf1[j], acc[i][j], 0, 0, 0);
    __builtin_amdgcn_s_setprio(0);

    buf = (buf == 2) ? 0 : buf + 1;
  }

  // ---- epilogue: bias add + direct (b,h,t,d) write. C/D: col=lane&15, row=(lane>>4)*4+reg ----
  const int crow = (lane >> 4) << 2;
  const int ccol = lane & 15;
  const int hh = n0 >> 6;
  const float* bias = wp ? bk : bq;
  f16* outp = wp ? ok : oq;
  #pragma unroll
  for (int j = 0; j < 4; j++) {
    const int col = n0 + j * 16 + ccol;
    const float bvl = bias[col];
    const int d = (j << 4) + ccol;
    #pragma unroll
    for (int i = 0; i < 4; i++) {
      #pragma unroll
      for (int r = 0; r < 4; r++) {
        const int row = m0 + wq * 64 + i * 16 + crow + r;
        const int b = row >> 11, t = row & (TSEQ - 1);
        outp[((size_t)(b * 16 + hh) * TSEQ + t) * 64 + d] = (f16)(acc[i][j][r] + bvl);
      }
    }
  }
}

// ---------------- small GEMM (K=1024): v-proj / p-proj ----------------
// MODE 0: fp16 out to (b,h,t,d) layout (v). MODE 1: fp32 out to (b,t,d) d_out (p).
template<int MODE>
__global__ __launch_bounds__(256, 2) void gemm_small(
    const f16* __restrict__ A, const f16* __restrict__ Bw,
    const float* __restrict__ bias, f16* __restrict__ oh, float* __restrict__ ofp)
{
  __shared__ f16 As[128 * 32];
  __shared__ f16 Bs[128 * 32];
  const int tid = threadIdx.x;
  const int lane = tid & 63;
  const int wid = tid >> 6;
  const int m0 = blockIdx.x * 128;
  const int n0 = blockIdx.y * 128;

  const int srow = lane >> 2;
  const int scg = ((lane & 3) ^ ((lane >> 3) & 3)) * 8;
  const int wm = wid & 1;
  const int wn = wid >> 1;

  f32x4 acc[4][4] = {};

  for (int kk = 0; kk < 1024; kk += 32) {
    __syncthreads();
    if (wid < 2) {
      #pragma unroll
      for (int c = 0; c < 4; c++) {
        const int r = wid * 64 + c * 16 + srow;
        const void* g = (const void*)(A + (((size_t)(m0 + r)) << 10) + kk + scg);
        gload_lds16(g, (void*)&As[(wid * 64 + c * 16) * 32]);
      }
    } else {
      #pragma unroll
      for (int c = 0; c < 4; c++) {
        const int r = (wid - 2) * 64 + c * 16 + srow;
        const void* g = (const void*)(Bw + (((size_t)(n0 + r)) << 10) + kk + scg);
        gload_lds16(g, (void*)&Bs[((wid - 2) * 64 + c * 16) * 32]);
      }
    }
    __syncthreads();
    const int koff = ((lane >> 4) ^ ((lane >> 1) & 3)) * 8;
    f16x8 af[4], bf[4];
    #pragma unroll
    for (int i = 0; i < 4; i++) {
      af[i] = *(const f16x8*)&As[(wm * 64 + i * 16 + (lane & 15)) * 32 + koff];
      bf[i] = *(const f16x8*)&Bs[(wn * 64 + i * 16 + (lane & 15)) * 32 + koff];
    }
    #pragma unroll
    for (int i = 0; i < 4; i++)
      #pragma unroll
      for (int j = 0; j < 4; j++)
        acc[i][j] = __builtin_amdgcn_mfma_f32_16x16x32_f16(af[i], bf[j], acc[i][j], 0, 0, 0);
  }

  const int crow = (lane >> 4) * 4;
  const int ccol = lane & 15;
  #pragma unroll
  for (int j = 0; j < 4; j++) {
    const int col = n0 + wn * 64 + j * 16 + ccol;
    const float bvl = bias[col];
    #pragma unroll
    for (int i = 0; i < 4; i++) {
      #pragma unroll
      for (int r = 0; r < 4; r++) {
        const int row = m0 + wm * 64 + i * 16 + crow + r;
        const float val = acc[i][j][r] + bvl;
        if (MODE == 1) {
          ofp[(size_t)row * DDIM + col] = val;
        } else {
          const int b = row >> 11, t = row & (TSEQ - 1);
          const int h = col >> 6, d = col & 63;
          oh[((size_t)(b * 16 + h) * TSEQ + t) * 64 + d] = (f16)val;
        }
      }
    }
  }
}

// ------- log-sparse scores, (b,h,t,d) layout, coalesced + fdot2 -------
__global__ __launch_bounds__(256) void score_k(const f16* __restrict__ qh,
                                               const f16* __restrict__ kh,
                                               float* __restrict__ scores) {
  const int bid = blockIdx.x;
  const int bh = bid >> 5, tc = bid & 31;
  const int tid = threadIdx.x;
  const int wave = tid >> 6, lane = tid & 63;
  const int tr = lane >> 3, dc = lane & 7;
  const size_t base = ((size_t)bh) << 17;
  const f16* qb = qh + base;
  const f16* kb = kh + base;

  #pragma unroll
  for (int p = 0; p < 2; p++) {
    const int t = tc * 64 + p * 32 + wave * 8 + tr;
    f16x8 qv = *(const f16x8*)(qb + (size_t)t * 64 + dc * 8);
    const f16x2* qp = (const f16x2*)&qv;
    #pragma unroll
    for (int e = 0; e < 8; e++) {
      const int ts = (t + (1 << e)) & (TSEQ - 1);
      f16x8 kv = *(const f16x8*)(kb + (size_t)ts * 64 + dc * 8);
      const f16x2* kp = (const f16x2*)&kv;
      float s = 0.f;
      #pragma unroll
      for (int j = 0; j < 4; j++) s = __builtin_amdgcn_fdot2(qp[j], kp[j], s, false);
      s += __shfl_xor(s, 1, 64);
      s += __shfl_xor(s, 2, 64);
      s += __shfl_xor(s, 4, 64);
      if (dc == 0) scores[((size_t)(bh * 8 + e) << 11) + t] = s * 0.125f;
    }
  }
}

// ---- in-place softmax over T per (b,h,e) row: 256 rows of 2048 ----
__global__ void softmax_k(float* __restrict__ scores) {
  __shared__ float red[4];
  int row = blockIdx.x;
  float* p = scores + ((size_t)row << 11);
  int tid = threadIdx.x;
  float v[8];
  float4 a = ((const float4*)p)[tid * 2];
  float4 b = ((const float4*)p)[tid * 2 + 1];
  v[0] = a.x; v[1] = a.y; v[2] = a.z; v[3] = a.w;
  v[4] = b.x; v[5] = b.y; v[6] = b.z; v[7] = b.w;
  float m = v[0];
  #pragma unroll
  for (int j = 1; j < 8; j++) m = fmaxf(m, v[j]);
  for (int o = 32; o > 0; o >>= 1) m = fmaxf(m, __shfl_xor(m, o, 64));
  if ((tid & 63) == 0) red[tid >> 6] = m;
  __syncthreads();
  m = fmaxf(fmaxf(red[0], red[1]), fmaxf(red[2], red[3]));
  __syncthreads();
  float s = 0.f;
  #pragma unroll
  for (int j = 0; j < 8; j++) { v[j] = __expf(v[j] - m); s += v[j]; }
  for (int o = 32; o > 0; o >>= 1) s += __shfl_xor(s, o, 64);
  if ((tid & 63) == 0) red[tid >> 6] = s;
  __syncthreads();
  s = (red[0] + red[1]) + (red[2] + red[3]);
  float inv = 1.0f / s;
  float4 o1 = make_float4(v[0] * inv, v[1] * inv, v[2] * inv, v[3] * inv);
  float4 o2 = make_float4(v[4] * inv, v[5] * inv, v[6] * inv, v[7] * inv);
  ((float4*)p)[tid * 2] = o1;
  ((float4*)p)[tid * 2 + 1] = o2;
}

// ------- local windowed attention + log-sparse combine -> outh (b,t,d) -------
__global__ __launch_bounds__(256) void attn_out_k(
    const f16* __restrict__ qh, const f16* __restrict__ kh, const f16* __restrict__ vh,
    const float* __restrict__ alpha, f16* __restrict__ outh)
{
  __shared__ f16 qL[64 * 64];
  __shared__ f16 kL[80 * 64];
  __shared__ f16 vL[208 * 64];
  __shared__ float scL[64 * 16];
  __shared__ float aL[8 * 64];
  const int bh = blockIdx.x, tc = blockIdx.y;
  const int t0 = tc * 64;
  const int tid = threadIdx.x;
  const size_t base = ((size_t)bh) << 17;

  for (int idx = tid; idx < 64 * 8; idx += 256) {
    int r = idx >> 3, c = idx & 7, sl = c ^ (r & 7);
    *(uint4*)&qL[r * 64 + sl * 8] = *(const uint4*)(qh + base + (size_t)(t0 + r) * 64 + c * 8);
  }
  for (int idx = tid; idx < 79 * 8; idx += 256) {
    int r = idx >> 3, c = idx & 7, sl = c ^ (r & 7);
    int g = t0 - 15 + r;
    uint4 val = (g < 0) ? make_uint4(0, 0, 0, 0)
                        : *(const uint4*)(kh + base + (size_t)g * 64 + c * 8);
    *(uint4*)&kL[r * 64 + sl * 8] = val;
  }
  for (int idx = tid; idx < 207 * 8; idx += 256) {
    int r = idx >> 3, c = idx & 7, sl = c ^ (r & 7);
    int g = t0 - 15 + r;
    uint4 val;
    if (g < 0) val = make_uint4(0, 0, 0, 0);
    else {
      if (g >= TSEQ) g -= TSEQ;
      val = *(const uint4*)(vh + base + (size_t)g * 64 + c * 8);
    }
    *(uint4*)&vL[r * 64 + sl * 8] = val;
  }
  for (int idx = tid; idx < 512; idx += 256) {
    int e = idx >> 6, i = idx & 63;
    aL[e * 64 + i] = alpha[((size_t)(bh * 8 + e) << 11) + t0 + i];
  }
  __syncthreads();

  {
    const int tl = tid & 63;
    const int wg = tid >> 6;
    f16x8 qv[8];
    #pragma unroll
    for (int c = 0; c < 8; c++) qv[c] = *(const f16x8*)&qL[tl * 64 + ((c ^ (tl & 7)) * 8)];
    const f16x2* qp = (const f16x2*)&qv[0];
    #pragma unroll
    for (int wi = 0; wi < 4; wi++) {
      const int w = wg * 4 + wi;
      const int r = tl + w;
      float s = 0.f;
      #pragma unroll
      for (int c = 0; c < 8; c++) {
        f16x8 kv = *(const f16x8*)&kL[r * 64 + ((c ^ (r & 7)) * 8)];
        const f16x2* kp = (const f16x2*)&kv;
        #pragma unroll
        for (int j = 0; j < 4; j++) s = __builtin_amdgcn_fdot2(qp[c * 4 + j], kp[j], s, false);
      }
      scL[tl * 16 + w] = s * 0.125f;
    }
  }
  __syncthreads();

  if (tid < 64) {
    float sc[16];
    float m = -1e30f;
    #pragma unroll
    for (int w = 0; w < 16; w++) { sc[w] = scL[tid * 16 + w]; m = fmaxf(m, sc[w]); }
    float sum = 0.f;
    #pragma unroll
    for (int w = 0; w < 16; w++) { sc[w] = __expf(sc[w] - m); sum += sc[w]; }
    float inv = 1.0f / sum;
    #pragma unroll
    for (int w = 0; w < 16; w++) scL[tid * 16 + w] = sc[w] * inv;
  }
  __syncthreads();

  {
    const int tl = tid >> 2;
    const int qd = tid & 3;
    float accv[16] = {};
    #pragma unroll
    for (int w = 0; w < 16; w++) {
      const float pw_ = scL[tl * 16 + w];
      const int r = tl + w;
      #pragma unroll
      for (int c2 = 0; c2 < 2; c2++) {
        const int c = qd * 2 + c2;
        f16x8 v = *(const f16x8*)&vL[r * 64 + ((c ^ (r & 7)) * 8)];
        #pragma unroll
        for (int j = 0; j < 8; j++) accv[c2 * 8 + j] += pw_ * (float)v[j];
      }
    }
    #pragma unroll
    for (int e = 0; e < 8; e++) {
      const float a = aL[e * 64 + tl];
      const int r = tl + 15 + (1 << e);
      #pragma unroll
      for (int c2 = 0; c2 < 2; c2++) {
        const int c = qd * 2 + c2;
        f16x8 v = *(const f16x8*)&vL[r * 64 + ((c ^ (r & 7)) * 8)];
        #pragma unroll
        for (int j = 0; j < 8; j++) accv[c2 * 8 + j] += a * (float)v[j];
      }
    }
    const int b = bh >> 4, h = bh & 15;
    f16* orow = outh + ((size_t)(b * TSEQ + t0 + tl)) * DDIM + h * 64 + qd * 16;
    #pragma unroll
    for (int c2 = 0; c2 < 2; c2++) {
      f16x8 v;
      #pragma unroll
      for (int j = 0; j < 8; j++) v[j] = (f16)accv[c2 * 8 + j];
      *(f16x8*)(orow + c2 * 8) = v;
    }
  }
}

extern "C" void kernel_launch(void* const* d_in, const int* in_sizes, int n_in,
                              void* d_out, int out_size, void* d_ws, size_t ws_size,
                              hipStream_t stream) {
  (void)in_sizes; (void)n_in; (void)out_size; (void)ws_size;
  const float* x   = (const float*)d_in[0];
  const float* q_w = (const float*)d_in[1];
  const float* q_b = (const float*)d_in[2];
  const float* k_w = (const float*)d_in[3];
  const float* k_b = (const float*)d_in[4];
  const float* v_w = (const float*)d_in[5];
  const float* v_b = (const float*)d_in[6];
  const float* p_w = (const float*)d_in[7];
  const float* p_b = (const float*)d_in[8];
  float* out = (float*)d_out;

  char* ws = (char*)d_ws;
  f16* xh      = (f16*)(ws);                 //  8.4 MB (b,t,d)
  f16* qwh     = (f16*)(ws + 8388608);       // 33.6 MB [o][w*1024+i]
  f16* kwh     = (f16*)(ws + 41943040);      // 33.6 MB [o][w*1024+i]
  f16* vwh     = (f16*)(ws + 75497472);      //  2.1 MB flat [o][k]
  f16* pwh     = (f16*)(ws + 77594624);      //  2.1 MB flat [o][k]
  f16* qh      = (f16*)(ws + 79691776);      //  8.4 MB (b,h,t,d)
  f16* kh      = (f16*)(ws + 88080384);      //  8.4 MB (b,h,t,d)
  f16* vh      = (f16*)(ws + 96468992);      //  8.4 MB (b,h,t,d)
  f16* outh    = (f16*)(ws + 104857600);     //  8.4 MB (b,t,d)
  float* alpha = (float*)(ws + 113246208);   //  2.1 MB (B*H*E, T)
  // total 115.4 MB

  static int s_attr_done = 0;
  if (!s_attr_done) {
    hipFuncSetAttribute((const void*)gemm_qk8,
                        hipFuncAttributeMaxDynamicSharedMemorySize, 147456);
    s_attr_done = 1;
  }

  cvt_all<<<6144, 256, 0, stream>>>(x, v_w, p_w, xh, vwh, pwh);
  cvt_w_tr<<<2048, 256, 0, stream>>>(q_w, k_w, qwh, kwh);

  // fused q+k conv-GEMM, 256 blocks = 1/CU, 144KB dynamic LDS, 1-barrier/K-tile pipeline
  gemm_qk8<<<dim3(16, 16), 512, 147456, stream>>>(xh, qwh, kwh, q_b, k_b, qh, kh);
  // v projection
  gemm_small<0><<<dim3(32, 8), 256, 0, stream>>>(xh, vwh, v_b, vh, nullptr);

  score_k<<<1024, 256, 0, stream>>>(qh, kh, alpha);
  softmax_k<<<256, 256, 0, stream>>>(alpha);
  attn_out_k<<<dim3(32, 32), 256, 0, stream>>>(qh, kh, vh, alpha, outh);

  // final projection -> fp32 d_out
  gemm_small<1><<<dim3(32, 8), 256, 0, stream>>>(outh, pwh, p_b, nullptr, out);
}

// Round 3
// 488.939 us; speedup vs baseline: 1.0936x; 1.0512x over previous
//
#include <hip/hip_runtime.h>
#include <cstdint>
#include <cstddef>

#define TSEQ 2048
#define DDIM 1024

typedef _Float16 f16;
typedef _Float16 f16x2 __attribute__((ext_vector_type(2)));
typedef _Float16 f16x4 __attribute__((ext_vector_type(4)));
typedef _Float16 f16x8 __attribute__((ext_vector_type(8)));
typedef float f32x4 __attribute__((ext_vector_type(4)));

// q,k,v live in (b,h,t,d) layout: ((b*16+h)*2048 + t)*64 + d.
// Conv weights for gemm_qk8 live in MFMA-FRAGMENT order:
//   Wf[nb][kt][f=j*2+s][lane][8] : value = W[o=nb*64+j*16+(lane&15)]
//                                         [tap w=kt&15][i=(kt>>4)*64+s*32+(lane>>4)*8+c]
// i.e. K-order is (i-block, tap) so 16 consecutive kt share the same x-rows (shifted).

__device__ __align__(16) static const unsigned char g_zero16[16] = {};

__device__ __forceinline__ void gload_lds16(const void* g, void* l) {
  __builtin_amdgcn_global_load_lds(
      (const __attribute__((address_space(1))) void*)g,
      (__attribute__((address_space(3))) void*)l, 16, 0, 0);
}

// ------------- fused fp32->fp16 converts (x, v_w, p_w) -------------
__global__ void cvt_all(const float* __restrict__ x, const float* __restrict__ vw,
                        const float* __restrict__ pw,
                        f16* __restrict__ xh, f16* __restrict__ vwh, f16* __restrict__ pwh) {
  int b = blockIdx.x;
  const float* src; f16* dst; int i;
  if (b < 4096)      { src = x;  dst = xh;  i = b * 256 + threadIdx.x; }
  else if (b < 5120) { src = vw; dst = vwh; i = (b - 4096) * 256 + threadIdx.x; }
  else               { src = pw; dst = pwh; i = (b - 5120) * 256 + threadIdx.x; }
  float4 v = ((const float4*)src)[i];
  f16x4 h = { (f16)v.x, (f16)v.y, (f16)v.z, (f16)v.w };
  ((f16x4*)dst)[i] = h;
}

// ------- conv weights w[o][i][W] -> fragment-ordered Wf (see header comment) -------
// 512 blocks: 256 q (4 o-rows each) then 256 k. Dynamic LDS 132096 B.
__global__ __launch_bounds__(256) void cvt_w_frag(const float* __restrict__ qw,
                                                  const float* __restrict__ kw,
                                                  f16* __restrict__ qd, f16* __restrict__ kd) {
  extern __shared__ f16 wt_lds[];    // 4 * 16 * 1032 f16
  const int bid = blockIdx.x;
  const float* src; f16* dst;
  int o0;
  if (bid < 256) { src = qw; dst = qd; o0 = bid * 4; }
  else           { src = kw; dst = kd; o0 = (bid - 256) * 4; }
  const int tid = threadIdx.x;
  // phase 1: stage 4 o-rows as tile[ro][w][i]  (row stride 1032 breaks conflicts)
  for (int p = 0; p < 64; p++) {
    const int idx = p * 256 + tid;          // 0..16383
    const int ro = idx >> 12;               // 0..3
    const int rem = idx & 4095;
    const int i = rem >> 2, wq2 = rem & 3;  // i-channel, w-quad
    float4 v = *(const float4*)(src + (size_t)(o0 + ro) * 16384 + (size_t)i * 16 + wq2 * 4);
    f16* trow = wt_lds + ro * 16512 + i;    // 16*1032 = 16512
    trow[(wq2 * 4 + 0) * 1032] = (f16)v.x;
    trow[(wq2 * 4 + 1) * 1032] = (f16)v.y;
    trow[(wq2 * 4 + 2) * 1032] = (f16)v.z;
    trow[(wq2 * 4 + 3) * 1032] = (f16)v.w;
  }
  __syncthreads();
  // phase 2: emit fragment order; each thread writes 4 consecutive 16B chunks (64B)
  const int jj = (o0 >> 4) & 3;
  const int nb = o0 >> 6;
  for (int p8 = 0; p8 < 8; p8++) {
    const int p = p8 * 256 + tid;           // 0..2047
    const int ktp = p >> 3;                 // K-tile 0..255, = ib*16 + w
    const int s = (p >> 2) & 1;             // K-slice within tile
    const int lhi = p & 3;                  // lane>>4
    const int w = ktp & 15;                 // tap
    const int ibb = ktp >> 4;               // i-block
    const int i0 = ibb * 64 + s * 32 + lhi * 8;
    const size_t dbase = (((size_t)(nb * 256 + ktp)) * 8 + jj * 2 + s) * 512;
    #pragma unroll
    for (int ro = 0; ro < 4; ro++) {
      const int l = lhi * 16 + ((o0 + ro) & 15);
      *(f16x8*)(dst + dbase + l * 8) =
          *(const f16x8*)&wt_lds[ro * 16512 + w * 1032 + i0];
    }
  }
}

// ------------- fused q+k conv-GEMM: A-slab in LDS, B direct global->VGPR -------------
// BM=256, BK=64, K-order (i-block, tap). Per i-block: stage 271-row x 64-ch slab once
// (34 KB), sweep 16 taps reading A-frags from the resident slab; B-frags double-buffered
// in registers from fragment-ordered weights. Barrier only at slab swap (17 total).
// A(ib)-completeness before sweep ib: every wave executes a compiler vmcnt wait for its
// B regs each tile; vmcnt is in-order, stageX(ib) is older than all sweep-(ib-1) B loads,
// so it is drained before every wave reaches the boundary barrier.
__global__ __launch_bounds__(512, 1) void gemm_qk8(
    const f16* __restrict__ xh,
    const f16* __restrict__ Wfq, const f16* __restrict__ Wfk,
    const float* __restrict__ bq, const float* __restrict__ bk,
    f16* __restrict__ oq, f16* __restrict__ ok)
{
  extern __shared__ __align__(16) f16 smem[];   // 2 * 17408 f16 = 68 KB
  const int tid = threadIdx.x;
  const int lane = tid & 63;
  const int wid = tid >> 6;          // 0..7
  const int wq = wid >> 1;           // M-quarter 0..3 (64 rows each)
  const int wp = wid & 1;            // 0 = q projection, 1 = k projection

  // XCD-bijective remap: each XCD owns 2 n-columns (weights fetched once per XCD)
  const int flat = blockIdx.y * 16 + blockIdx.x;
  const int xcd = flat & 7;
  const int idx = flat >> 3;                  // 0..31
  const int nblk = xcd * 2 + (idx >> 4);
  const int mblk = idx & 15;
  const int m0 = mblk * 256;
  const int n0 = nblk * 64;
  const int bT = m0 & ~(TSEQ - 1);
  const int t0 = m0 & (TSEQ - 1);

  // staging swizzle: lane l writes LDS slot (l&7); global chunk = (l&7)^(row&7)
  const int srow = lane >> 3;
  const int chunk8 = (((lane & 7) ^ (srow & 7)) << 3);

  const f16* Wf = wp ? Wfk : Wfq;
  const f16* wbase = Wf + ((size_t)nblk << 20) + lane * 8;   // nblk * 1048576 f16

  f32x4 acc[4][4] = {};
  f16x8 bfr[2][8];

  // stage the 271-row x 64-channel slab for i-block ib2 (34 groups of 8 rows)
  auto stageX = [&](int ib2, int bufp) {
    f16* sb = smem + bufp * 17408;
    const int ic = ib2 * 64 + chunk8;
    #pragma unroll
    for (int c = 0; c < 5; c++) {
      const int g = c * 8 + wid;
      if (g < 34) {
        const int srcT = t0 + g * 8 + srow - 15;
        const void* gp = (srcT >= 0)
            ? (const void*)(xh + (((size_t)(bT + srcT)) << 10) + ic)
            : (const void*)g_zero16;
        gload_lds16(gp, (void*)&sb[g * 512]);
      }
    }
  };

  auto loadB = [&](int kt, f16x8* bf) {
    const f16* p = wbase + ((size_t)kt << 12);   // kt * 4096 f16
    #pragma unroll
    for (int f = 0; f < 8; f++)
      bf[f] = *(const f16x8*)(p + f * 512);
  };

  // prologue
  stageX(0, 0);
  loadB(0, bfr[0]);
  asm volatile("s_waitcnt vmcnt(0)" ::: "memory");
  __builtin_amdgcn_s_barrier();
  __builtin_amdgcn_sched_barrier(0);

  for (int ib = 0; ib < 16; ib++) {
    if (ib > 0) {
      __builtin_amdgcn_s_barrier();
      __builtin_amdgcn_sched_barrier(0);
    }
    if (ib + 1 < 16) stageX(ib + 1, (ib + 1) & 1);
    __builtin_amdgcn_sched_barrier(0);
    const f16* xb = smem + (ib & 1) * 17408;
    #pragma unroll
    for (int wt = 0; wt < 16; wt++) {
      const int kt = ib * 16 + wt;
      const int rx = ((lane & 7) + wt) & 7;              // (row+tap)&7
      const int sl0 = (((lane >> 4)) ^ rx) << 3;         // slice 0 slot
      const int sl1 = (((lane >> 4) + 4) ^ rx) << 3;     // slice 1 slot
      f16x8 af[8];
      #pragma unroll
      for (int i = 0; i < 4; i++) {
        const int row = wq * 64 + i * 16 + (lane & 15) + wt;
        af[i]     = *(const f16x8*)&xb[row * 64 + sl0];
        af[4 + i] = *(const f16x8*)&xb[row * 64 + sl1];
      }
      if (kt + 1 < 256) loadB(kt + 1, bfr[(wt & 1) ^ 1]);
      __builtin_amdgcn_s_setprio(1);
      #pragma unroll
      for (int i = 0; i < 4; i++)
        #pragma unroll
        for (int j = 0; j < 4; j++)
          acc[i][j] = __builtin_amdgcn_mfma_f32_16x16x32_f16(
              af[i], bfr[wt & 1][2 * j], acc[i][j], 0, 0, 0);
      #pragma unroll
      for (int i = 0; i < 4; i++)
        #pragma unroll
        for (int j = 0; j < 4; j++)
          acc[i][j] = __builtin_amdgcn_mfma_f32_16x16x32_f16(
              af[4 + i], bfr[wt & 1][2 * j + 1], acc[i][j], 0, 0, 0);
      __builtin_amdgcn_s_setprio(0);
    }
  }

  // ---- epilogue: bias add + direct (b,h,t,d) write. C/D: col=lane&15, row=(lane>>4)*4+reg ----
  const int crow = (lane >> 4) << 2;
  const int ccol = lane & 15;
  const int hh = n0 >> 6;
  const float* bias = wp ? bk : bq;
  f16* outp = wp ? ok : oq;
  #pragma unroll
  for (int j = 0; j < 4; j++) {
    const int col = n0 + j * 16 + ccol;
    const float bvl = bias[col];
    const int d = (j << 4) + ccol;
    #pragma unroll
    for (int i = 0; i < 4; i++) {
      #pragma unroll
      for (int r = 0; r < 4; r++) {
        const int row = m0 + wq * 64 + i * 16 + crow + r;
        const int b = row >> 11, t = row & (TSEQ - 1);
        outp[((size_t)(b * 16 + hh) * TSEQ + t) * 64 + d] = (f16)(acc[i][j][r] + bvl);
      }
    }
  }
}

// ---------------- small GEMM (K=1024): v-proj / p-proj ----------------
// MODE 0: fp16 out to (b,h,t,d) layout (v). MODE 1: fp32 out to (b,t,d) d_out (p).
template<int MODE>
__global__ __launch_bounds__(256, 2) void gemm_small(
    const f16* __restrict__ A, const f16* __restrict__ Bw,
    const float* __restrict__ bias, f16* __restrict__ oh, float* __restrict__ ofp)
{
  __shared__ f16 As[128 * 32];
  __shared__ f16 Bs[128 * 32];
  const int tid = threadIdx.x;
  const int lane = tid & 63;
  const int wid = tid >> 6;
  const int m0 = blockIdx.x * 128;
  const int n0 = blockIdx.y * 128;

  const int srow = lane >> 2;
  const int scg = ((lane & 3) ^ ((lane >> 3) & 3)) * 8;
  const int wm = wid & 1;
  const int wn = wid >> 1;

  f32x4 acc[4][4] = {};

  for (int kk = 0; kk < 1024; kk += 32) {
    __syncthreads();
    if (wid < 2) {
      #pragma unroll
      for (int c = 0; c < 4; c++) {
        const int r = wid * 64 + c * 16 + srow;
        const void* g = (const void*)(A + (((size_t)(m0 + r)) << 10) + kk + scg);
        gload_lds16(g, (void*)&As[(wid * 64 + c * 16) * 32]);
      }
    } else {
      #pragma unroll
      for (int c = 0; c < 4; c++) {
        const int r = (wid - 2) * 64 + c * 16 + srow;
        const void* g = (const void*)(Bw + (((size_t)(n0 + r)) << 10) + kk + scg);
        gload_lds16(g, (void*)&Bs[((wid - 2) * 64 + c * 16) * 32]);
      }
    }
    __syncthreads();
    const int koff = ((lane >> 4) ^ ((lane >> 1) & 3)) * 8;
    f16x8 af[4], bf[4];
    #pragma unroll
    for (int i = 0; i < 4; i++) {
      af[i] = *(const f16x8*)&As[(wm * 64 + i * 16 + (lane & 15)) * 32 + koff];
      bf[i] = *(const f16x8*)&Bs[(wn * 64 + i * 16 + (lane & 15)) * 32 + koff];
    }
    #pragma unroll
    for (int i = 0; i < 4; i++)
      #pragma unroll
      for (int j = 0; j < 4; j++)
        acc[i][j] = __builtin_amdgcn_mfma_f32_16x16x32_f16(af[i], bf[j], acc[i][j], 0, 0, 0);
  }

  const int crow = (lane >> 4) * 4;
  const int ccol = lane & 15;
  #pragma unroll
  for (int j = 0; j < 4; j++) {
    const int col = n0 + wn * 64 + j * 16 + ccol;
    const float bvl = bias[col];
    #pragma unroll
    for (int i = 0; i < 4; i++) {
      #pragma unroll
      for (int r = 0; r < 4; r++) {
        const int row = m0 + wm * 64 + i * 16 + crow + r;
        const float val = acc[i][j][r] + bvl;
        if (MODE == 1) {
          ofp[(size_t)row * DDIM + col] = val;
        } else {
          const int b = row >> 11, t = row & (TSEQ - 1);
          const int h = col >> 6, d = col & 63;
          oh[((size_t)(b * 16 + h) * TSEQ + t) * 64 + d] = (f16)val;
        }
      }
    }
  }
}

// ------- log-sparse scores, (b,h,t,d) layout, coalesced + fdot2 -------
__global__ __launch_bounds__(256) void score_k(const f16* __restrict__ qh,
                                               const f16* __restrict__ kh,
                                               float* __restrict__ scores) {
  const int bid = blockIdx.x;
  const int bh = bid >> 5, tc = bid & 31;
  const int tid = threadIdx.x;
  const int wave = tid >> 6, lane = tid & 63;
  const int tr = lane >> 3, dc = lane & 7;
  const size_t base = ((size_t)bh) << 17;
  const f16* qb = qh + base;
  const f16* kb = kh + base;

  #pragma unroll
  for (int p = 0; p < 2; p++) {
    const int t = tc * 64 + p * 32 + wave * 8 + tr;
    f16x8 qv = *(const f16x8*)(qb + (size_t)t * 64 + dc * 8);
    const f16x2* qp = (const f16x2*)&qv;
    #pragma unroll
    for (int e = 0; e < 8; e++) {
      const int ts = (t + (1 << e)) & (TSEQ - 1);
      f16x8 kv = *(const f16x8*)(kb + (size_t)ts * 64 + dc * 8);
      const f16x2* kp = (const f16x2*)&kv;
      float s = 0.f;
      #pragma unroll
      for (int j = 0; j < 4; j++) s = __builtin_amdgcn_fdot2(qp[j], kp[j], s, false);
      s += __shfl_xor(s, 1, 64);
      s += __shfl_xor(s, 2, 64);
      s += __shfl_xor(s, 4, 64);
      if (dc == 0) scores[((size_t)(bh * 8 + e) << 11) + t] = s * 0.125f;
    }
  }
}

// ---- in-place softmax over T per (b,h,e) row: 256 rows of 2048 ----
__global__ void softmax_k(float* __restrict__ scores) {
  __shared__ float red[4];
  int row = blockIdx.x;
  float* p = scores + ((size_t)row << 11);
  int tid = threadIdx.x;
  float v[8];
  float4 a = ((const float4*)p)[tid * 2];
  float4 b = ((const float4*)p)[tid * 2 + 1];
  v[0] = a.x; v[1] = a.y; v[2] = a.z; v[3] = a.w;
  v[4] = b.x; v[5] = b.y; v[6] = b.z; v[7] = b.w;
  float m = v[0];
  #pragma unroll
  for (int j = 1; j < 8; j++) m = fmaxf(m, v[j]);
  for (int o = 32; o > 0; o >>= 1) m = fmaxf(m, __shfl_xor(m, o, 64));
  if ((tid & 63) == 0) red[tid >> 6] = m;
  __syncthreads();
  m = fmaxf(fmaxf(red[0], red[1]), fmaxf(red[2], red[3]));
  __syncthreads();
  float s = 0.f;
  #pragma unroll
  for (int j = 0; j < 8; j++) { v[j] = __expf(v[j] - m); s += v[j]; }
  for (int o = 32; o > 0; o >>= 1) s += __shfl_xor(s, o, 64);
  if ((tid & 63) == 0) red[tid >> 6] = s;
  __syncthreads();
  s = (red[0] + red[1]) + (red[2] + red[3]);
  float inv = 1.0f / s;
  float4 o1 = make_float4(v[0] * inv, v[1] * inv, v[2] * inv, v[3] * inv);
  float4 o2 = make_float4(v[4] * inv, v[5] * inv, v[6] * inv, v[7] * inv);
  ((float4*)p)[tid * 2] = o1;
  ((float4*)p)[tid * 2 + 1] = o2;
}

// ------- local windowed attention + log-sparse combine -> outh (b,t,d) -------
__global__ __launch_bounds__(256) void attn_out_k(
    const f16* __restrict__ qh, const f16* __restrict__ kh, const f16* __restrict__ vh,
    const float* __restrict__ alpha, f16* __restrict__ outh)
{
  __shared__ f16 qL[64 * 64];
  __shared__ f16 kL[80 * 64];
  __shared__ f16 vL[208 * 64];
  __shared__ float scL[64 * 16];
  __shared__ float aL[8 * 64];
  const int bh = blockIdx.x, tc = blockIdx.y;
  const int t0 = tc * 64;
  const int tid = threadIdx.x;
  const size_t base = ((size_t)bh) << 17;

  for (int idx = tid; idx < 64 * 8; idx += 256) {
    int r = idx >> 3, c = idx & 7, sl = c ^ (r & 7);
    *(uint4*)&qL[r * 64 + sl * 8] = *(const uint4*)(qh + base + (size_t)(t0 + r) * 64 + c * 8);
  }
  for (int idx = tid; idx < 79 * 8; idx += 256) {
    int r = idx >> 3, c = idx & 7, sl = c ^ (r & 7);
    int g = t0 - 15 + r;
    uint4 val = (g < 0) ? make_uint4(0, 0, 0, 0)
                        : *(const uint4*)(kh + base + (size_t)g * 64 + c * 8);
    *(uint4*)&kL[r * 64 + sl * 8] = val;
  }
  for (int idx = tid; idx < 207 * 8; idx += 256) {
    int r = idx >> 3, c = idx & 7, sl = c ^ (r & 7);
    int g = t0 - 15 + r;
    uint4 val;
    if (g < 0) val = make_uint4(0, 0, 0, 0);
    else {
      if (g >= TSEQ) g -= TSEQ;
      val = *(const uint4*)(vh + base + (size_t)g * 64 + c * 8);
    }
    *(uint4*)&vL[r * 64 + sl * 8] = val;
  }
  for (int idx = tid; idx < 512; idx += 256) {
    int e = idx >> 6, i = idx & 63;
    aL[e * 64 + i] = alpha[((size_t)(bh * 8 + e) << 11) + t0 + i];
  }
  __syncthreads();

  {
    const int tl = tid & 63;
    const int wg = tid >> 6;
    f16x8 qv[8];
    #pragma unroll
    for (int c = 0; c < 8; c++) qv[c] = *(const f16x8*)&qL[tl * 64 + ((c ^ (tl & 7)) * 8)];
    const f16x2* qp = (const f16x2*)&qv[0];
    #pragma unroll
    for (int wi = 0; wi < 4; wi++) {
      const int w = wg * 4 + wi;
      const int r = tl + w;
      float s = 0.f;
      #pragma unroll
      for (int c = 0; c < 8; c++) {
        f16x8 kv = *(const f16x8*)&kL[r * 64 + ((c ^ (r & 7)) * 8)];
        const f16x2* kp = (const f16x2*)&kv;
        #pragma unroll
        for (int j = 0; j < 4; j++) s = __builtin_amdgcn_fdot2(qp[c * 4 + j], kp[j], s, false);
      }
      scL[tl * 16 + w] = s * 0.125f;
    }
  }
  __syncthreads();

  if (tid < 64) {
    float sc[16];
    float m = -1e30f;
    #pragma unroll
    for (int w = 0; w < 16; w++) { sc[w] = scL[tid * 16 + w]; m = fmaxf(m, sc[w]); }
    float sum = 0.f;
    #pragma unroll
    for (int w = 0; w < 16; w++) { sc[w] = __expf(sc[w] - m); sum += sc[w]; }
    float inv = 1.0f / sum;
    #pragma unroll
    for (int w = 0; w < 16; w++) scL[tid * 16 + w] = sc[w] * inv;
  }
  __syncthreads();

  {
    const int tl = tid >> 2;
    const int qd = tid & 3;
    float accv[16] = {};
    #pragma unroll
    for (int w = 0; w < 16; w++) {
      const float pw_ = scL[tl * 16 + w];
      const int r = tl + w;
      #pragma unroll
      for (int c2 = 0; c2 < 2; c2++) {
        const int c = qd * 2 + c2;
        f16x8 v = *(const f16x8*)&vL[r * 64 + ((c ^ (r & 7)) * 8)];
        #pragma unroll
        for (int j = 0; j < 8; j++) accv[c2 * 8 + j] += pw_ * (float)v[j];
      }
    }
    #pragma unroll
    for (int e = 0; e < 8; e++) {
      const float a = aL[e * 64 + tl];
      const int r = tl + 15 + (1 << e);
      #pragma unroll
      for (int c2 = 0; c2 < 2; c2++) {
        const int c = qd * 2 + c2;
        f16x8 v = *(const f16x8*)&vL[r * 64 + ((c ^ (r & 7)) * 8)];
        #pragma unroll
        for (int j = 0; j < 8; j++) accv[c2 * 8 + j] += a * (float)v[j];
      }
    }
    const int b = bh >> 4, h = bh & 15;
    f16* orow = outh + ((size_t)(b * TSEQ + t0 + tl)) * DDIM + h * 64 + qd * 16;
    #pragma unroll
    for (int c2 = 0; c2 < 2; c2++) {
      f16x8 v;
      #pragma unroll
      for (int j = 0; j < 8; j++) v[j] = (f16)accv[c2 * 8 + j];
      *(f16x8*)(orow + c2 * 8) = v;
    }
  }
}

extern "C" void kernel_launch(void* const* d_in, const int* in_sizes, int n_in,
                              void* d_out, int out_size, void* d_ws, size_t ws_size,
                              hipStream_t stream) {
  (void)in_sizes; (void)n_in; (void)out_size; (void)ws_size;
  const float* x   = (const float*)d_in[0];
  const float* q_w = (const float*)d_in[1];
  const float* q_b = (const float*)d_in[2];
  const float* k_w = (const float*)d_in[3];
  const float* k_b = (const float*)d_in[4];
  const float* v_w = (const float*)d_in[5];
  const float* v_b = (const float*)d_in[6];
  const float* p_w = (const float*)d_in[7];
  const float* p_b = (const float*)d_in[8];
  float* out = (float*)d_out;

  char* ws = (char*)d_ws;
  f16* xh      = (f16*)(ws);                 //  8.4 MB (b,t,d)
  f16* qwh     = (f16*)(ws + 8388608);       // 33.6 MB fragment-ordered Wfq
  f16* kwh     = (f16*)(ws + 41943040);      // 33.6 MB fragment-ordered Wfk
  f16* vwh     = (f16*)(ws + 75497472);      //  2.1 MB flat [o][k]
  f16* pwh     = (f16*)(ws + 77594624);      //  2.1 MB flat [o][k]
  f16* qh      = (f16*)(ws + 79691776);      //  8.4 MB (b,h,t,d)
  f16* kh      = (f16*)(ws + 88080384);      //  8.4 MB (b,h,t,d)
  f16* vh      = (f16*)(ws + 96468992);      //  8.4 MB (b,h,t,d)
  f16* outh    = (f16*)(ws + 104857600);     //  8.4 MB (b,t,d)
  float* alpha = (float*)(ws + 113246208);   //  2.1 MB (B*H*E, T)
  // total 115.4 MB

  static int s_attr_done = 0;
  if (!s_attr_done) {
    hipFuncSetAttribute((const void*)gemm_qk8,
                        hipFuncAttributeMaxDynamicSharedMemorySize, 69632);
    hipFuncSetAttribute((const void*)cvt_w_frag,
                        hipFuncAttributeMaxDynamicSharedMemorySize, 132096);
    s_attr_done = 1;
  }

  cvt_all<<<6144, 256, 0, stream>>>(x, v_w, p_w, xh, vwh, pwh);
  cvt_w_frag<<<512, 256, 132096, stream>>>(q_w, k_w, qwh, kwh);

  // fused q+k conv-GEMM: A-slab LDS (68KB dyn), B direct to regs, 256 blocks = 1/CU
  gemm_qk8<<<dim3(16, 16), 512, 69632, stream>>>(xh, qwh, kwh, q_b, k_b, qh, kh);
  // v projection
  gemm_small<0><<<dim3(32, 8), 256, 0, stream>>>(xh, vwh, v_b, vh, nullptr);

  score_k<<<1024, 256, 0, stream>>>(qh, kh, alpha);
  softmax_k<<<256, 256, 0, stream>>>(alpha);
  attn_out_k<<<dim3(32, 32), 256, 0, stream>>>(qh, kh, vh, alpha, outh);

  // final projection -> fp32 d_out
  gemm_small<1><<<dim3(32, 8), 256, 0, stream>>>(outh, pwh, p_b, nullptr, out);
}